// Round 5
// baseline (130.610 us; speedup 1.0000x reference)
//
#include <hip/hip_runtime.h>

#define NN 1024
#define FF 128

typedef __attribute__((ext_vector_type(8))) short bf16x8;
typedef __attribute__((ext_vector_type(4))) float f32x4;

__device__ __forceinline__ unsigned short f2bf(float x) {
  unsigned u = __float_as_uint(x);
  u += 0x7fff + ((u >> 16) & 1);   // round-to-nearest-even
  return (unsigned short)(u >> 16);
}
__device__ __forceinline__ float bf2f(unsigned short b) {
  return __uint_as_float(((unsigned)b) << 16);
}
__device__ __forceinline__ bf16x8 cvt8(float4 a, float4 b) {
  bf16x8 r;
  r[0] = (short)f2bf(a.x); r[1] = (short)f2bf(a.y);
  r[2] = (short)f2bf(a.z); r[3] = (short)f2bf(a.w);
  r[4] = (short)f2bf(b.x); r[5] = (short)f2bf(b.y);
  r[6] = (short)f2bf(b.z); r[7] = (short)f2bf(b.w);
  return r;
}

// async global->LDS, 16B per lane. LDS dest = wave-uniform base + lane*16.
__device__ __forceinline__ void gl_lds16(const void* g, void* l) {
  __builtin_amdgcn_global_load_lds(
      (const __attribute__((address_space(1))) unsigned*)g,
      (__attribute__((address_space(3))) unsigned*)l, 16, 0, 0);
}

// ---------------------------------------------------------------------------
// K0: Wt[g][f] = bf16(W[f][g])  (tiny)
// ---------------------------------------------------------------------------
__global__ __launch_bounds__(256) void k_wt(const float* __restrict__ W,
                                            unsigned short* __restrict__ Wt) {
  int id = blockIdx.x * 256 + threadIdx.x;
  int g = id >> 7, f = id & 127;
  Wt[g * 128 + f] = f2bf(W[f * 128 + g]);
}

// ---------------------------------------------------------------------------
// K1 (fused deg + XW): block owns 64 m-rows of one batch.
// Phase 1: deg/d + Abf=bf16(A) for own rows (4 waves x 16 rows, 4-row load
//          batching for ILP); d kept in LDS, also written to global for k_agg.
// Phase 2: Yt[b][g][m] = bf16( d[m] * sum_f X[m,f]*W[f,g] )  (MFMA, K=128).
// XOR-swizzled LDS: row r, 16B chunk c stored at pos c^(r&15).
// ---------------------------------------------------------------------------
__global__ __launch_bounds__(256) void k_pre(const float* __restrict__ A,
                                             const float* __restrict__ X,
                                             const unsigned short* __restrict__ Wt,
                                             float* __restrict__ d,
                                             unsigned short* __restrict__ Abf,
                                             unsigned short* __restrict__ Yt) {
  __shared__ __align__(16) unsigned short Xs[64 * 128];
  __shared__ __align__(16) unsigned short Ws[128 * 128];
  __shared__ float dl[64];
  int t  = threadIdx.x;
  int b  = blockIdx.x >> 4;
  int m0 = (blockIdx.x & 15) * 64;
  int wave = t >> 6, lane = t & 63;

  // ---- phase 1: rows m0 + wave*16 .. +15 ----
  {
    float rs[16];
#pragma unroll
    for (int i0 = 0; i0 < 16; i0 += 4) {
      float4 v[4][4];
#pragma unroll
      for (int i = 0; i < 4; ++i) {
        size_t grow = (size_t)b * NN + m0 + wave * 16 + i0 + i;
        const float4* Ar = (const float4*)(A + grow * NN);
#pragma unroll
        for (int k = 0; k < 4; ++k) v[i][k] = Ar[lane + k * 64];
      }
#pragma unroll
      for (int i = 0; i < 4; ++i) {
        size_t grow = (size_t)b * NN + m0 + wave * 16 + i0 + i;
        unsigned short* Br = Abf + grow * NN;
        float s = 0.f;
#pragma unroll
        for (int k = 0; k < 4; ++k) {
          float4 w = v[i][k];
          ushort4 p; p.x = f2bf(w.x); p.y = f2bf(w.y); p.z = f2bf(w.z); p.w = f2bf(w.w);
          *(ushort4*)(Br + (lane + k * 64) * 4) = p;
          s += (w.x + w.y) + (w.z + w.w);
        }
        rs[i0 + i] = s;
      }
    }
#pragma unroll
    for (int i = 0; i < 16; ++i) {
      float s = rs[i];
#pragma unroll
      for (int off = 32; off > 0; off >>= 1) s += __shfl_down(s, off, 64);
      if (lane == 0) {
        float dv = rsqrtf(s + 1.0f);
        int r = wave * 16 + i;
        dl[r] = dv;
        d[(size_t)b * NN + m0 + r] = dv;
      }
    }
  }

  // ---- stage X (own 64 rows, fp32->bf16, swizzled) + Wt (bf16, swizzled) ----
#pragma unroll
  for (int j = 0; j < 4; ++j) {
    int id = t + j * 256;
    int r = id >> 4, p = id & 15, c = p ^ (r & 15);
    const float* gp = X + ((size_t)(b * NN + m0 + r) * FF + c * 8);
    float4 v0 = *(const float4*)gp;
    float4 v1 = *(const float4*)(gp + 4);
    *(bf16x8*)&Xs[r * 128 + p * 8] = cvt8(v0, v1);
  }
#pragma unroll
  for (int j = 0; j < 8; ++j) {
    int id = t + j * 256;
    int g = id >> 4, p = id & 15, c = p ^ (g & 15);
    uint4 v = *(const uint4*)(Wt + g * 128 + c * 8);
    *(uint4*)&Ws[g * 128 + p * 8] = v;
  }
  __syncthreads();

  // ---- phase 2: XW GEMM (wave: 16 m x 128 g) ----
  int quad = lane >> 4, l16 = lane & 15;
  f32x4 acc[8];
#pragma unroll
  for (int ct = 0; ct < 8; ++ct) acc[ct] = (f32x4){0.f, 0.f, 0.f, 0.f};

#pragma unroll
  for (int ks = 0; ks < 4; ++ks) {
    int q = ks * 4 + quad;
    bf16x8 a = *(const bf16x8*)&Xs[(wave * 16 + l16) * 128 + (q ^ l16) * 8];
#pragma unroll
    for (int ct = 0; ct < 8; ++ct) {
      bf16x8 w = *(const bf16x8*)&Ws[(ct * 16 + l16) * 128 + (q ^ l16) * 8];
      acc[ct] = __builtin_amdgcn_mfma_f32_16x16x32_bf16(a, w, acc[ct], 0, 0, 0);
    }
  }

  int mb = wave * 16 + quad * 4;
  float4 d4 = *(const float4*)&dl[mb];
#pragma unroll
  for (int ct = 0; ct < 8; ++ct) {
    int g = ct * 16 + l16;
    ushort4 p;
    p.x = f2bf(d4.x * acc[ct][0]);
    p.y = f2bf(d4.y * acc[ct][1]);
    p.z = f2bf(d4.z * acc[ct][2]);
    p.w = f2bf(d4.w * acc[ct][3]);
    *(ushort4*)(Yt + (size_t)(b * 128 + g) * NN + m0 + mb) = p;
  }
}

// ---------------------------------------------------------------------------
// K2: out[b,n,g] = d[n] * ( sum_m Abf[b,n,m]*Yt[b,g,m] + Yt[b,g,n] )
// Per-batch GEMM 1024x128x1024. BM=32, BN=128, BK=128, 8 stages.
// Double-buffered LDS (80KB -> 2 blocks/CU), staged ONLY by global_load_lds.
// ONE barrier per stage: barrier drains stage-s loads (issued a full compute
// stage ago), then stage-s+1 loads are issued and fly during stage-s MFMAs.
// XCD swizzle: all 32 blocks of a batch share bid&7 -> same XCD -> Yt (256KB)
// L2-resident per XCD.
// ---------------------------------------------------------------------------
__global__ __launch_bounds__(256, 2) void k_agg(const unsigned short* __restrict__ Abf,
                                                const unsigned short* __restrict__ Yt,
                                                const float* __restrict__ d,
                                                float* __restrict__ out) {
  __shared__ __align__(16) unsigned short As[2][32 * 128];
  __shared__ __align__(16) unsigned short Ys[2][128 * 128];
  int t   = threadIdx.x;
  int bid = blockIdx.x;
  int xcd = bid & 7;
  int j   = bid >> 3;                    // 0..63
  int b   = xcd + 8 * (j >> 5);          // batch: same XCD for all its blocks
  int n0  = (j & 31) * 32;
  int wave = t >> 6, lane = t & 63, quad = lane >> 4, l16 = lane & 15;
  int wr = wave >> 1, wc = wave & 1;
  int rl = lane >> 4, pl = lane & 15;    // staging: row-within-4, chunk pos

  const unsigned short* Ab = Abf + (size_t)(b * NN + n0) * NN;
  const unsigned short* Yb = Yt + (size_t)b * 128 * NN;

  auto issue = [&](int k0, int buf) {
#pragma unroll
    for (int jj = 0; jj < 2; ++jj) {     // A: 32 rows x 256B
      int r0 = wave * 8 + jj * 4;
      int r  = r0 + rl;
      int c  = pl ^ (r & 15);
      gl_lds16(Ab + ((size_t)r * NN + k0 + c * 8), &As[buf][r0 * 128]);
    }
#pragma unroll
    for (int jj = 0; jj < 8; ++jj) {     // Y: 128 rows x 256B
      int r0 = wave * 32 + jj * 4;
      int r  = r0 + rl;
      int c  = pl ^ (r & 15);
      gl_lds16(Yb + ((size_t)r * NN + k0 + c * 8), &Ys[buf][r0 * 128]);
    }
  };

  f32x4 acc[4];
#pragma unroll
  for (int ct = 0; ct < 4; ++ct) acc[ct] = (f32x4){0.f, 0.f, 0.f, 0.f};

  issue(0, 0);
  for (int s = 0; s < 8; ++s) {
    int cur = s & 1;
    __syncthreads();                     // drain: stage-s data in LDS
    if (s < 7) issue((s + 1) * 128, cur ^ 1);   // fly during stage-s compute
#pragma unroll
    for (int ks = 0; ks < 4; ++ks) {
      int cq = ks * 4 + quad;
      bf16x8 a = *(const bf16x8*)&As[cur][(wr * 16 + l16) * 128 + (cq ^ l16) * 8];
#pragma unroll
      for (int ct = 0; ct < 4; ++ct) {
        bf16x8 y = *(const bf16x8*)&Ys[cur][(wc * 64 + ct * 16 + l16) * 128 + (cq ^ l16) * 8];
        acc[ct] = __builtin_amdgcn_mfma_f32_16x16x32_bf16(a, y, acc[ct], 0, 0, 0);
      }
    }
  }

  // epilogue: out[n,g] = d[n]*(acc + Yt[g][n]); C/D: row = quad*4+reg, col = l16
  int nb = n0 + wr * 16 + quad * 4;
  float4 d4 = *(const float4*)(d + b * NN + nb);
#pragma unroll
  for (int ct = 0; ct < 4; ++ct) {
    int g = wc * 64 + ct * 16 + l16;
    ushort4 yv = *(const ushort4*)(Yt + (size_t)(b * 128 + g) * NN + nb);
    float* op = out + ((size_t)(b * NN + nb) * FF + g);
    op[0 * FF] = d4.x * (acc[ct][0] + bf2f(yv.x));
    op[1 * FF] = d4.y * (acc[ct][1] + bf2f(yv.y));
    op[2 * FF] = d4.z * (acc[ct][2] + bf2f(yv.z));
    op[3 * FF] = d4.w * (acc[ct][3] + bf2f(yv.w));
  }
}

// ---------------------------------------------------------------------------
extern "C" void kernel_launch(void* const* d_in, const int* in_sizes, int n_in,
                              void* d_out, int out_size, void* d_ws, size_t ws_size,
                              hipStream_t stream) {
  const float* X = (const float*)d_in[0];  // [16,1024,128]
  const float* A = (const float*)d_in[1];  // [16,1024,1024]
  const float* W = (const float*)d_in[2];  // [128,128]
  float* out = (float*)d_out;              // [16,1024,128]

  char* ws = (char*)d_ws;
  float*          dinv = (float*)ws;                                    // 64 KB
  unsigned short* Wt   = (unsigned short*)(ws + 65536);                 // 32 KB
  unsigned short* Yt   = (unsigned short*)(ws + 98304);                 // 4 MB [b][g][m]
  unsigned short* Abf  = (unsigned short*)(ws + 98304 + 4194304);       // 32 MB bf16(A)

  k_wt <<<dim3(64),  dim3(256), 0, stream>>>(W, Wt);
  k_pre<<<dim3(256), dim3(256), 0, stream>>>(A, X, Wt, dinv, Abf, Yt);
  k_agg<<<dim3(512), dim3(256), 0, stream>>>(Abf, Yt, dinv, out);
}

// Round 6
// 121.791 us; speedup vs baseline: 1.0724x; 1.0724x over previous
//
#include <hip/hip_runtime.h>

#define NN 1024
#define FF 128

typedef __attribute__((ext_vector_type(8))) short bf16x8;
typedef __attribute__((ext_vector_type(4))) float f32x4;

__device__ __forceinline__ unsigned short f2bf(float x) {
  unsigned u = __float_as_uint(x);
  u += 0x7fff + ((u >> 16) & 1);   // round-to-nearest-even
  return (unsigned short)(u >> 16);
}
__device__ __forceinline__ float bf2f(unsigned short b) {
  return __uint_as_float(((unsigned)b) << 16);
}
__device__ __forceinline__ bf16x8 cvt8(float4 a, float4 b) {
  bf16x8 r;
  r[0] = (short)f2bf(a.x); r[1] = (short)f2bf(a.y);
  r[2] = (short)f2bf(a.z); r[3] = (short)f2bf(a.w);
  r[4] = (short)f2bf(b.x); r[5] = (short)f2bf(b.y);
  r[6] = (short)f2bf(b.z); r[7] = (short)f2bf(b.w);
  return r;
}

// async global->LDS, 16B per lane. LDS dest = wave-uniform base + lane*16.
__device__ __forceinline__ void gl_lds16(const void* g, void* l) {
  __builtin_amdgcn_global_load_lds(
      (const __attribute__((address_space(1))) unsigned*)g,
      (__attribute__((address_space(3))) unsigned*)l, 16, 0, 0);
}

// ---------------------------------------------------------------------------
// K1: deg[b,n] = 1 + sum_m A[b,n,m]; d = rsqrt(deg). One wave per row.
// Pure read (no Abf write) — A is left L3-resident for k_agg.
// Tail blocks (>=4096) build Wt[g][f] = bf16(W[f][g]).
// ---------------------------------------------------------------------------
__global__ __launch_bounds__(256) void k_deg(const float* __restrict__ A,
                                             const float* __restrict__ W,
                                             float* __restrict__ d,
                                             unsigned short* __restrict__ Wt) {
  if (blockIdx.x >= 4096) {
    int id = (blockIdx.x - 4096) * 256 + threadIdx.x;
    int g = id >> 7, f = id & 127;
    Wt[g * 128 + f] = f2bf(W[f * 128 + g]);
    return;
  }
  int row  = blockIdx.x * 4 + (threadIdx.x >> 6);
  int lane = threadIdx.x & 63;
  const float4* Ar = (const float4*)(A + (size_t)row * NN);
  float s = 0.f;
#pragma unroll
  for (int i = 0; i < 4; ++i) {
    float4 v = Ar[lane + i * 64];
    s += (v.x + v.y) + (v.z + v.w);
  }
#pragma unroll
  for (int off = 32; off > 0; off >>= 1) s += __shfl_down(s, off, 64);
  if (lane == 0) d[row] = rsqrtf(s + 1.0f);
}

// ---------------------------------------------------------------------------
// K2: Yt[b][g][m] = bf16( d[b,m] * sum_f X[b,m,f] * W[f,g] )
// LDS-staged, single K-stage (K=128). Block: 64 m-rows x 128 g, 4 waves.
// XOR-swizzled LDS (16B chunks): row r, chunk c stored at pos c^(r&15).
// ---------------------------------------------------------------------------
__global__ __launch_bounds__(256) void k_xw(const float* __restrict__ X,
                                            const unsigned short* __restrict__ Wt,
                                            const float* __restrict__ d,
                                            unsigned short* __restrict__ Yt) {
  __shared__ __align__(16) unsigned short Xs[64 * 128];
  __shared__ __align__(16) unsigned short Ws[128 * 128];
  __shared__ float dl[64];
  int t  = threadIdx.x;
  int b  = blockIdx.x >> 4;
  int m0 = (blockIdx.x & 15) * 64;

#pragma unroll
  for (int j = 0; j < 4; ++j) {
    int id = t + j * 256;
    int r = id >> 4, p = id & 15, c = p ^ (r & 15);
    const float* gp = X + ((size_t)(b * NN + m0 + r) * FF + c * 8);
    float4 v0 = *(const float4*)gp;
    float4 v1 = *(const float4*)(gp + 4);
    *(bf16x8*)&Xs[r * 128 + p * 8] = cvt8(v0, v1);
  }
#pragma unroll
  for (int j = 0; j < 8; ++j) {
    int id = t + j * 256;
    int g = id >> 4, p = id & 15, c = p ^ (g & 15);
    uint4 v = *(const uint4*)(Wt + g * 128 + c * 8);
    *(uint4*)&Ws[g * 128 + p * 8] = v;
  }
  if (t < 64) dl[t] = d[b * NN + m0 + t];
  __syncthreads();

  int wave = t >> 6, lane = t & 63, quad = lane >> 4, l16 = lane & 15;
  f32x4 acc[8];
#pragma unroll
  for (int ct = 0; ct < 8; ++ct) acc[ct] = (f32x4){0.f, 0.f, 0.f, 0.f};

#pragma unroll
  for (int ks = 0; ks < 4; ++ks) {
    int q = ks * 4 + quad;
    bf16x8 a = *(const bf16x8*)&Xs[(wave * 16 + l16) * 128 + (q ^ l16) * 8];
#pragma unroll
    for (int ct = 0; ct < 8; ++ct) {
      bf16x8 w = *(const bf16x8*)&Ws[(ct * 16 + l16) * 128 + (q ^ l16) * 8];
      acc[ct] = __builtin_amdgcn_mfma_f32_16x16x32_bf16(a, w, acc[ct], 0, 0, 0);
    }
  }

  int mb = wave * 16 + quad * 4;
  float4 d4 = *(const float4*)&dl[mb];
#pragma unroll
  for (int ct = 0; ct < 8; ++ct) {
    int g = ct * 16 + l16;
    ushort4 p;
    p.x = f2bf(d4.x * acc[ct][0]);
    p.y = f2bf(d4.y * acc[ct][1]);
    p.z = f2bf(d4.z * acc[ct][2]);
    p.w = f2bf(d4.w * acc[ct][3]);
    *(ushort4*)(Yt + (size_t)(b * 128 + g) * NN + m0 + mb) = p;
  }
}

// ---------------------------------------------------------------------------
// K3: out[b,n,g] = d[n] * ( sum_m A[b,n,m]*Yt[b,g,m] + Yt[b,g,n] )
// Per-batch GEMM 1024x128x1024, A read as RAW FP32 (L3-resident after k_deg;
// no Abf intermediate). BM=32, BN=128, BK=128, 8 stages, single 48KB LDS
// buffer (A fp32 16KB + Y bf16 32KB) -> 3 blocks/CU; co-resident blocks hide
// each other's barrier drains (this beat dbuf in R4 vs R5). Staging ONLY via
// global_load_lds; fp32->bf16 conversion after ds_read (in-register).
// A swizzle: row r, 16B chunk c at pos c ^ (2*(r&15)) (even XOR keeps the
// two b128s of an 8-float fragment adjacent).
// ---------------------------------------------------------------------------
__global__ __launch_bounds__(256) void k_agg(const float* __restrict__ A,
                                             const unsigned short* __restrict__ Yt,
                                             const float* __restrict__ d,
                                             float* __restrict__ out) {
  __shared__ __align__(16) float          Asf[32 * 128];      // fp32 A tile
  __shared__ __align__(16) unsigned short Ys[128 * 128];      // bf16 Y tile
  int t  = threadIdx.x;
  int b  = blockIdx.x >> 5;
  int n0 = (blockIdx.x & 31) * 32;
  int wave = t >> 6, lane = t & 63, quad = lane >> 4, l16 = lane & 15;
  int wr = wave >> 1, wc = wave & 1;
  int rl = lane >> 4, pl = lane & 15;   // Y staging: row-within-4, chunk pos
  int rh = lane >> 5, cc = lane & 31;   // A staging: row-within-2, chunk pos

  const float*          Ab = A  + (size_t)(b * NN + n0) * NN;
  const unsigned short* Yb = Yt + (size_t)b * 128 * NN;

  auto issue = [&](int k0) {
#pragma unroll
    for (int jj = 0; jj < 4; ++jj) {     // A: 32 rows x 512B fp32
      int r0 = wave * 8 + jj * 2;
      int r  = r0 + rh;
      int c  = cc ^ (2 * (r & 15));
      gl_lds16(Ab + ((size_t)r * NN + k0 + c * 4), &Asf[r0 * 128]);
    }
#pragma unroll
    for (int jj = 0; jj < 8; ++jj) {     // Y: 128 rows x 256B bf16
      int r0 = wave * 32 + jj * 4;
      int r  = r0 + rl;
      int c  = pl ^ (r & 15);
      gl_lds16(Yb + ((size_t)r * NN + k0 + c * 8), &Ys[r0 * 128]);
    }
  };

  f32x4 acc[4];
#pragma unroll
  for (int ct = 0; ct < 4; ++ct) acc[ct] = (f32x4){0.f, 0.f, 0.f, 0.f};

  int swA = 2 * l16;                     // even XOR for A-frag positions
  issue(0);
  for (int s = 0; s < 8; ++s) {
    __syncthreads();                     // stage-s data in LDS
#pragma unroll
    for (int ks = 0; ks < 4; ++ks) {
      int cq = ks * 4 + quad;
      int pa = (2 * cq) ^ swA;           // chunk pos of 8-float fragment
      float4 a0 = *(const float4*)&Asf[(wr * 16 + l16) * 128 + pa * 4];
      float4 a1 = *(const float4*)&Asf[(wr * 16 + l16) * 128 + pa * 4 + 4];
      bf16x8 a = cvt8(a0, a1);
#pragma unroll
      for (int ct = 0; ct < 4; ++ct) {
        bf16x8 y = *(const bf16x8*)&Ys[(wc * 64 + ct * 16 + l16) * 128 + ((cq ^ l16)) * 8];
        acc[ct] = __builtin_amdgcn_mfma_f32_16x16x32_bf16(a, y, acc[ct], 0, 0, 0);
      }
    }
    __syncthreads();                     // all waves done reading stage s
    if (s < 7) issue((s + 1) * 128);
  }

  // epilogue: out[n,g] = d[n]*(acc + Yt[g][n]); C/D: row = quad*4+reg, col = l16
  int nb = n0 + wr * 16 + quad * 4;
  float4 d4 = *(const float4*)(d + b * NN + nb);
#pragma unroll
  for (int ct = 0; ct < 4; ++ct) {
    int g = wc * 64 + ct * 16 + l16;
    ushort4 yv = *(const ushort4*)(Yt + (size_t)(b * 128 + g) * NN + nb);
    float* op = out + ((size_t)(b * NN + nb) * FF + g);
    op[0 * FF] = d4.x * (acc[ct][0] + bf2f(yv.x));
    op[1 * FF] = d4.y * (acc[ct][1] + bf2f(yv.y));
    op[2 * FF] = d4.z * (acc[ct][2] + bf2f(yv.z));
    op[3 * FF] = d4.w * (acc[ct][3] + bf2f(yv.w));
  }
}

// ---------------------------------------------------------------------------
extern "C" void kernel_launch(void* const* d_in, const int* in_sizes, int n_in,
                              void* d_out, int out_size, void* d_ws, size_t ws_size,
                              hipStream_t stream) {
  const float* X = (const float*)d_in[0];  // [16,1024,128]
  const float* A = (const float*)d_in[1];  // [16,1024,1024]
  const float* W = (const float*)d_in[2];  // [128,128]
  float* out = (float*)d_out;              // [16,1024,128]

  char* ws = (char*)d_ws;
  float*          dinv = (float*)ws;                    // 64 KB
  unsigned short* Wt   = (unsigned short*)(ws + 65536); // 32 KB
  unsigned short* Yt   = (unsigned short*)(ws + 98304); // 4 MB [b][g][m]

  k_deg<<<dim3(4096 + 64), dim3(256), 0, stream>>>(A, W, dinv, Wt);
  k_xw <<<dim3(256),       dim3(256), 0, stream>>>(X, Wt, dinv, Yt);
  k_agg<<<dim3(512),       dim3(256), 0, stream>>>(A, Yt, dinv, out);
}

// Round 7
// 119.564 us; speedup vs baseline: 1.0924x; 1.0186x over previous
//
#include <hip/hip_runtime.h>

#define NN 1024
#define FF 128

typedef __attribute__((ext_vector_type(8))) short bf16x8;
typedef __attribute__((ext_vector_type(4))) float f32x4;

__device__ __forceinline__ unsigned short f2bf(float x) {
  unsigned u = __float_as_uint(x);
  u += 0x7fff + ((u >> 16) & 1);   // round-to-nearest-even
  return (unsigned short)(u >> 16);
}
__device__ __forceinline__ float bf2f(unsigned short b) {
  return __uint_as_float(((unsigned)b) << 16);
}
__device__ __forceinline__ bf16x8 cvt8(float4 a, float4 b) {
  bf16x8 r;
  r[0] = (short)f2bf(a.x); r[1] = (short)f2bf(a.y);
  r[2] = (short)f2bf(a.z); r[3] = (short)f2bf(a.w);
  r[4] = (short)f2bf(b.x); r[5] = (short)f2bf(b.y);
  r[6] = (short)f2bf(b.z); r[7] = (short)f2bf(b.w);
  return r;
}

// async global->LDS, 16B per lane. LDS dest = wave-uniform base + lane*16.
__device__ __forceinline__ void gl_lds16(const void* g, void* l) {
  __builtin_amdgcn_global_load_lds(
      (const __attribute__((address_space(1))) unsigned*)g,
      (__attribute__((address_space(3))) unsigned*)l, 16, 0, 0);
}

// ---------------------------------------------------------------------------
// K1: deg[b,n] = 1 + sum_m A[b,n,m]; d = rsqrt(deg). One wave per row.
// Pure read — leaves A L3-resident for k_agg.
// Tail blocks (>=4096) build Wt[g][f] = bf16(W[f][g]).
// ---------------------------------------------------------------------------
__global__ __launch_bounds__(256) void k_deg(const float* __restrict__ A,
                                             const float* __restrict__ W,
                                             float* __restrict__ d,
                                             unsigned short* __restrict__ Wt) {
  if (blockIdx.x >= 4096) {
    int id = (blockIdx.x - 4096) * 256 + threadIdx.x;
    int g = id >> 7, f = id & 127;
    Wt[g * 128 + f] = f2bf(W[f * 128 + g]);
    return;
  }
  int row  = blockIdx.x * 4 + (threadIdx.x >> 6);
  int lane = threadIdx.x & 63;
  const float4* Ar = (const float4*)(A + (size_t)row * NN);
  float s = 0.f;
#pragma unroll
  for (int i = 0; i < 4; ++i) {
    float4 v = Ar[lane + i * 64];
    s += (v.x + v.y) + (v.z + v.w);
  }
#pragma unroll
  for (int off = 32; off > 0; off >>= 1) s += __shfl_down(s, off, 64);
  if (lane == 0) d[row] = rsqrtf(s + 1.0f);
}

// ---------------------------------------------------------------------------
// K2: Yt[b][g][m] = bf16( d[b,m] * sum_f X[b,m,f] * W[f,g] )
// LDS-staged, single K-stage (K=128). Block: 64 m-rows x 128 g, 4 waves.
// XOR-swizzled LDS (16B chunks): row r, chunk c stored at pos c^(r&15).
// ---------------------------------------------------------------------------
__global__ __launch_bounds__(256) void k_xw(const float* __restrict__ X,
                                            const unsigned short* __restrict__ Wt,
                                            const float* __restrict__ d,
                                            unsigned short* __restrict__ Yt) {
  __shared__ __align__(16) unsigned short Xs[64 * 128];
  __shared__ __align__(16) unsigned short Ws[128 * 128];
  __shared__ float dl[64];
  int t  = threadIdx.x;
  int b  = blockIdx.x >> 4;
  int m0 = (blockIdx.x & 15) * 64;

#pragma unroll
  for (int j = 0; j < 4; ++j) {
    int id = t + j * 256;
    int r = id >> 4, p = id & 15, c = p ^ (r & 15);
    const float* gp = X + ((size_t)(b * NN + m0 + r) * FF + c * 8);
    float4 v0 = *(const float4*)gp;
    float4 v1 = *(const float4*)(gp + 4);
    *(bf16x8*)&Xs[r * 128 + p * 8] = cvt8(v0, v1);
  }
#pragma unroll
  for (int j = 0; j < 8; ++j) {
    int id = t + j * 256;
    int g = id >> 4, p = id & 15, c = p ^ (g & 15);
    uint4 v = *(const uint4*)(Wt + g * 128 + c * 8);
    *(uint4*)&Ws[g * 128 + p * 8] = v;
  }
  if (t < 64) dl[t] = d[b * NN + m0 + t];
  __syncthreads();

  int wave = t >> 6, lane = t & 63, quad = lane >> 4, l16 = lane & 15;
  f32x4 acc[8];
#pragma unroll
  for (int ct = 0; ct < 8; ++ct) acc[ct] = (f32x4){0.f, 0.f, 0.f, 0.f};

#pragma unroll
  for (int ks = 0; ks < 4; ++ks) {
    int q = ks * 4 + quad;
    bf16x8 a = *(const bf16x8*)&Xs[(wave * 16 + l16) * 128 + (q ^ l16) * 8];
#pragma unroll
    for (int ct = 0; ct < 8; ++ct) {
      bf16x8 w = *(const bf16x8*)&Ws[(ct * 16 + l16) * 128 + (q ^ l16) * 8];
      acc[ct] = __builtin_amdgcn_mfma_f32_16x16x32_bf16(a, w, acc[ct], 0, 0, 0);
    }
  }

  int mb = wave * 16 + quad * 4;
  float4 d4 = *(const float4*)&dl[mb];
#pragma unroll
  for (int ct = 0; ct < 8; ++ct) {
    int g = ct * 16 + l16;
    ushort4 p;
    p.x = f2bf(d4.x * acc[ct][0]);
    p.y = f2bf(d4.y * acc[ct][1]);
    p.z = f2bf(d4.z * acc[ct][2]);
    p.w = f2bf(d4.w * acc[ct][3]);
    *(ushort4*)(Yt + (size_t)(b * 128 + g) * NN + m0 + mb) = p;
  }
}

// ---------------------------------------------------------------------------
// K3: out[b,n,g] = d[n] * ( sum_m A[b,n,m]*Yt[b,g,m] + Yt[b,g,n] )
// Per-batch GEMM 1024x128x1024, A read as RAW FP32 (L3-resident after k_deg).
// BM=32, BN=128, BK=128, 8 stages, single 48KB LDS buffer -> 3 blocks/CU.
// XCD swizzle: bid&7 selects XCD under round-robin dispatch; all 32 blocks
// of a batch share one XCD -> that batch's Yt (256KB) stays L2-resident
// (2 batches/XCD = 512KB of 4MB L2) instead of 16-batch/4MB thrash.
// Staging ONLY via global_load_lds; fp32->bf16 conversion after ds_read.
// ---------------------------------------------------------------------------
__global__ __launch_bounds__(256) void k_agg(const float* __restrict__ A,
                                             const unsigned short* __restrict__ Yt,
                                             const float* __restrict__ d,
                                             float* __restrict__ out) {
  __shared__ __align__(16) float          Asf[32 * 128];      // fp32 A tile
  __shared__ __align__(16) unsigned short Ys[128 * 128];      // bf16 Y tile
  int t   = threadIdx.x;
  int bid = blockIdx.x;
  int xcd = bid & 7;
  int j   = bid >> 3;                    // 0..63
  int b   = xcd + 8 * (j >> 5);          // all 32 blocks of batch b on one XCD
  int n0  = (j & 31) * 32;
  int wave = t >> 6, lane = t & 63, quad = lane >> 4, l16 = lane & 15;
  int wr = wave >> 1, wc = wave & 1;
  int rl = lane >> 4, pl = lane & 15;   // Y staging: row-within-4, chunk pos
  int rh = lane >> 5, cc = lane & 31;   // A staging: row-within-2, chunk pos

  const float*          Ab = A  + (size_t)(b * NN + n0) * NN;
  const unsigned short* Yb = Yt + (size_t)b * 128 * NN;

  auto issue = [&](int k0) {
#pragma unroll
    for (int jj = 0; jj < 4; ++jj) {     // A: 32 rows x 512B fp32
      int r0 = wave * 8 + jj * 2;
      int r  = r0 + rh;
      int c  = cc ^ (2 * (r & 15));
      gl_lds16(Ab + ((size_t)r * NN + k0 + c * 4), &Asf[r0 * 128]);
    }
#pragma unroll
    for (int jj = 0; jj < 8; ++jj) {     // Y: 128 rows x 256B bf16
      int r0 = wave * 32 + jj * 4;
      int r  = r0 + rl;
      int c  = pl ^ (r & 15);
      gl_lds16(Yb + ((size_t)r * NN + k0 + c * 8), &Ys[r0 * 128]);
    }
  };

  f32x4 acc[4];
#pragma unroll
  for (int ct = 0; ct < 4; ++ct) acc[ct] = (f32x4){0.f, 0.f, 0.f, 0.f};

  int swA = 2 * l16;                     // even XOR for A-frag positions
  issue(0);
  for (int s = 0; s < 8; ++s) {
    __syncthreads();                     // stage-s data in LDS
#pragma unroll
    for (int ks = 0; ks < 4; ++ks) {
      int cq = ks * 4 + quad;
      int pa = (2 * cq) ^ swA;           // chunk pos of 8-float fragment
      float4 a0 = *(const float4*)&Asf[(wr * 16 + l16) * 128 + pa * 4];
      float4 a1 = *(const float4*)&Asf[(wr * 16 + l16) * 128 + pa * 4 + 4];
      bf16x8 a = cvt8(a0, a1);
#pragma unroll
      for (int ct = 0; ct < 4; ++ct) {
        bf16x8 y = *(const bf16x8*)&Ys[(wc * 64 + ct * 16 + l16) * 128 + ((cq ^ l16)) * 8];
        acc[ct] = __builtin_amdgcn_mfma_f32_16x16x32_bf16(a, y, acc[ct], 0, 0, 0);
      }
    }
    __syncthreads();                     // all waves done reading stage s
    if (s < 7) issue((s + 1) * 128);
  }

  // epilogue: out[n,g] = d[n]*(acc + Yt[g][n]); C/D: row = quad*4+reg, col = l16
  int nb = n0 + wr * 16 + quad * 4;
  float4 d4 = *(const float4*)(d + b * NN + nb);
#pragma unroll
  for (int ct = 0; ct < 4; ++ct) {
    int g = wc * 64 + ct * 16 + l16;
    ushort4 yv = *(const ushort4*)(Yt + (size_t)(b * 128 + g) * NN + nb);
    float* op = out + ((size_t)(b * NN + nb) * FF + g);
    op[0 * FF] = d4.x * (acc[ct][0] + bf2f(yv.x));
    op[1 * FF] = d4.y * (acc[ct][1] + bf2f(yv.y));
    op[2 * FF] = d4.z * (acc[ct][2] + bf2f(yv.z));
    op[3 * FF] = d4.w * (acc[ct][3] + bf2f(yv.w));
  }
}

// ---------------------------------------------------------------------------
extern "C" void kernel_launch(void* const* d_in, const int* in_sizes, int n_in,
                              void* d_out, int out_size, void* d_ws, size_t ws_size,
                              hipStream_t stream) {
  const float* X = (const float*)d_in[0];  // [16,1024,128]
  const float* A = (const float*)d_in[1];  // [16,1024,1024]
  const float* W = (const float*)d_in[2];  // [128,128]
  float* out = (float*)d_out;              // [16,1024,128]

  char* ws = (char*)d_ws;
  float*          dinv = (float*)ws;                    // 64 KB
  unsigned short* Wt   = (unsigned short*)(ws + 65536); // 32 KB
  unsigned short* Yt   = (unsigned short*)(ws + 98304); // 4 MB [b][g][m]

  k_deg<<<dim3(4096 + 64), dim3(256), 0, stream>>>(A, W, dinv, Wt);
  k_xw <<<dim3(256),       dim3(256), 0, stream>>>(X, Wt, dinv, Yt);
  k_agg<<<dim3(512),       dim3(256), 0, stream>>>(A, Yt, dinv, out);
}